// Round 2
// baseline (436.584 us; speedup 1.0000x reference)
//
#include <hip/hip_runtime.h>
#include <hip/hip_bf16.h>
#include <math.h>

#define NB 16
#define NT 2048
#define ND 512
#define NH 64

// ---------------------------------------------------------------------------
// mask dtype robustness: harness may ship jnp bool as int32 (0/1), as raw
// bytes, or even as f32. lengths >= T/2, so mask[0..3] (b=0,t=0..3) are all
// true. Byte layout -> first int32 reads 0x01010101; int32 layout -> 1;
// f32 layout -> 0x3F800000. So: int32-indexed access is correct unless the
// first word is exactly 0x01010101.
// ---------------------------------------------------------------------------
__device__ __forceinline__ bool mask_is_bytes(const int* m) {
    return m[0] == 0x01010101;
}
__device__ __forceinline__ bool mask_at(const int* m, bool bytes, int i) {
    if (bytes) return ((const unsigned char*)m)[i] != 0;
    return m[i] != 0;
}

// Minkowski dot with metric folded into `a` = (E, -px, -py, -pz).
// Explicit fmaf so pass 1 and pass 2 produce bitwise-identical values.
__device__ __forceinline__ float dot4(float4 a, float4 p) {
    float d = a.x * p.x;
    d = __builtin_fmaf(a.y, p.y, d);
    d = __builtin_fmaf(a.z, p.z, d);
    d = __builtin_fmaf(a.w, p.w, d);
    return d;
}

// ---------------------------------------------------------------------------
// Kernel A: tokens_cont -> four-vectors P. Masked s-slots get (-1e30,0,0,0)
// so their dot with any valid row (~ -1e30*E_t) is far below every real dot
// (|real dot| <= ~3e5) and they can never enter a valid row's top-8.
// ---------------------------------------------------------------------------
__global__ void __launch_bounds__(256) compute_P_kernel(
        const float* __restrict__ tok,
        const int* __restrict__ mask,
        float4* __restrict__ P) {
    const bool mb = mask_is_bytes(mask);
    int i = blockIdx.x * 256 + threadIdx.x;
    if (i >= NB * NT) return;
    float4 t = ((const float4*)tok)[i];
    float E = t.x, Pt = t.y, eta = t.z, phi = t.w;
    float px = Pt * cosf(phi);
    float py = Pt * sinf(phi);
    float pz = Pt * sinhf(fminf(fmaxf(eta, -20.f), 20.f));
    bool m = mask_at(mask, mb, i);
    P[i] = m ? make_float4(E, px, py, pz)
             : make_float4(-1e30f, 0.f, 0.f, 0.f);
}

// ---------------------------------------------------------------------------
// Kernel B: per token t, scan all s: pass 1 keeps top-8 dot VALUES via a
// branchless med3 chain; pass 2 re-scans and accumulates P-sums for
// d >= {v1, v3, v7} (top-2/4/8 membership). Then invariant masses.
// One wave per 64 tokens; s-index is wave-uniform -> scalar loads.
// ---------------------------------------------------------------------------
__global__ void __launch_bounds__(64) topk_mass_kernel(
        const float4* __restrict__ P,
        const int* __restrict__ mask,
        float* __restrict__ massOut) {
    const int b    = blockIdx.y;
    const int t0   = blockIdx.x * 64;
    const int lane = threadIdx.x;
    const int t    = t0 + lane;
    const float4* Pb = P + b * NT;
    const bool mb = mask_is_bytes(mask);

    // mask is monotone per row (t < lengths[b]); if the first t of this wave
    // is masked, all 64 are -> early out with mass = sqrt(1e-8).
    if (!mask_at(mask, mb, b * NT + t0)) {
        float mz = sqrtf(1e-8f);
        int o = (b * NT + t) * 3;
        massOut[o + 0] = mz;
        massOut[o + 1] = mz;
        massOut[o + 2] = mz;
        return;
    }

    const bool maskt = mask_at(mask, mb, b * NT + t);
    float4 pt = Pb[t];
    float4 a  = make_float4(pt.x, -pt.y, -pt.z, -pt.w);

    const float NEGBIG = -3.402823466e38f;
    float v0 = NEGBIG, v1 = NEGBIG, v2 = NEGBIG, v3 = NEGBIG;
    float v4 = NEGBIG, v5 = NEGBIG, v6 = NEGBIG, v7 = NEGBIG;

    // Pass 1: top-8 values. Sorted-descending invariant v0>=...>=v7.
    // new v[i] = median(d, v[i-1], v[i]) — all reads from OLD regs (ILP-8).
#pragma unroll 4
    for (int s = 0; s < NT; ++s) {
        float4 ps = Pb[s];          // wave-uniform -> scalar load
        float d = dot4(a, ps);
        float n0 = fmaxf(v0, d);
        float n1 = __builtin_amdgcn_fmed3f(d, v0, v1);
        float n2 = __builtin_amdgcn_fmed3f(d, v1, v2);
        float n3 = __builtin_amdgcn_fmed3f(d, v2, v3);
        float n4 = __builtin_amdgcn_fmed3f(d, v3, v4);
        float n5 = __builtin_amdgcn_fmed3f(d, v4, v5);
        float n6 = __builtin_amdgcn_fmed3f(d, v5, v6);
        float n7 = __builtin_amdgcn_fmed3f(d, v6, v7);
        v0 = n0; v1 = n1; v2 = n2; v3 = n3;
        v4 = n4; v5 = n5; v6 = n6; v7 = n7;
    }

    const float th2 = v1, th4 = v3, th8 = v7;   // th2 >= th4 >= th8

    float s2x = 0.f, s2y = 0.f, s2z = 0.f, s2w = 0.f;
    float s4x = 0.f, s4y = 0.f, s4z = 0.f, s4w = 0.f;
    float s8x = 0.f, s8y = 0.f, s8z = 0.f, s8w = 0.f;

    // Pass 2: membership accumulate. d recomputed bitwise-identically, so
    // d >= th8 hits exactly the 8 selected s (ties measure-zero).
#pragma unroll 4
    for (int s = 0; s < NT; ++s) {
        float4 ps = Pb[s];
        float d = dot4(a, ps);
        if (d >= th8) {
            s8x += ps.x; s8y += ps.y; s8z += ps.z; s8w += ps.w;
            if (d >= th4) {
                s4x += ps.x; s4y += ps.y; s4z += ps.z; s4w += ps.w;
                if (d >= th2) {
                    s2x += ps.x; s2y += ps.y; s2z += ps.z; s2w += ps.w;
                }
            }
        }
    }

    // mass_k = sqrt(max(E^2 - |p|^2, 0) * maskf + 1e-8)
    auto massf = [&](float sx, float sy, float sz, float sw) -> float {
        float m2 = sx * sx;
        m2 = __builtin_fmaf(-sy, sy, m2);
        m2 = __builtin_fmaf(-sz, sz, m2);
        m2 = __builtin_fmaf(-sw, sw, m2);
        m2 = fmaxf(m2, 0.f);
        if (!maskt) m2 = 0.f;          // handles inf/NaN on masked rows
        return sqrtf(m2 + 1e-8f);
    };

    int o = (b * NT + t) * 3;
    massOut[o + 0] = massf(s2x, s2y, s2z, s2w);
    massOut[o + 1] = massf(s4x, s4y, s4z, s4w);
    massOut[o + 2] = massf(s8x, s8y, s8z, s8w);
}

// ---------------------------------------------------------------------------
// Kernel C: mass(3) -> gelu(mass@W1+b1)(64) in LDS -> @W2+b2 (512).
// Block = 256 threads, 64 tokens per block. h stored k-major so the GEMM
// phase reads 4 tokens per ds_read_b128.
// ---------------------------------------------------------------------------
__global__ void __launch_bounds__(256) mlp_kernel(
        const float* __restrict__ mass,
        const float* __restrict__ W1,
        const float* __restrict__ b1,
        const float* __restrict__ W2,
        const float* __restrict__ b2,
        float* __restrict__ out) {
    __shared__ float hs[NH][64];        // [k][token]

    const int tid = threadIdx.x;
    const int tokBase = blockIdx.x * 64;

    // Stage 1: h = gelu(mass @ W1 + b1). 16 h-values per thread;
    // hh is wave-uniform -> W1/b1 come in as scalar loads.
    {
        const int tt = tid & 63;
        const int hr = tid >> 6;        // 0..3, wave-uniform
        const int tokg = tokBase + tt;
        float m0 = mass[tokg * 3 + 0];
        float m1 = mass[tokg * 3 + 1];
        float m2 = mass[tokg * 3 + 2];
#pragma unroll
        for (int j = 0; j < 16; ++j) {
            int hh = hr + j * 4;
            float pre = b1[hh];
            pre = __builtin_fmaf(m0, W1[hh], pre);
            pre = __builtin_fmaf(m1, W1[NH + hh], pre);
            pre = __builtin_fmaf(m2, W1[2 * NH + hh], pre);
            float g = 0.5f * pre * (1.0f + erff(pre * 0.70710678118654752f));
            hs[hh][tt] = g;
        }
    }
    __syncthreads();

    // Stage 2: out = h @ W2 + b2. Thread = (tg, dg): 4 tokens x 4 d,
    // looped over 8 d-chunks of 64.
    const int dg = tid & 15;
    const int tg = tid >> 4;
    const int t0 = tg * 4;

    for (int dc = 0; dc < 8; ++dc) {
        const int d0 = dc * 64 + dg * 4;
        float a00 = 0, a01 = 0, a02 = 0, a03 = 0;
        float a10 = 0, a11 = 0, a12 = 0, a13 = 0;
        float a20 = 0, a21 = 0, a22 = 0, a23 = 0;
        float a30 = 0, a31 = 0, a32 = 0, a33 = 0;
#pragma unroll 4
        for (int k = 0; k < NH; ++k) {
            float4 hv = *(const float4*)&hs[k][t0];
            float4 wv = *(const float4*)&W2[k * ND + d0];
            a00 = __builtin_fmaf(hv.x, wv.x, a00);
            a01 = __builtin_fmaf(hv.x, wv.y, a01);
            a02 = __builtin_fmaf(hv.x, wv.z, a02);
            a03 = __builtin_fmaf(hv.x, wv.w, a03);
            a10 = __builtin_fmaf(hv.y, wv.x, a10);
            a11 = __builtin_fmaf(hv.y, wv.y, a11);
            a12 = __builtin_fmaf(hv.y, wv.z, a12);
            a13 = __builtin_fmaf(hv.y, wv.w, a13);
            a20 = __builtin_fmaf(hv.z, wv.x, a20);
            a21 = __builtin_fmaf(hv.z, wv.y, a21);
            a22 = __builtin_fmaf(hv.z, wv.z, a22);
            a23 = __builtin_fmaf(hv.z, wv.w, a23);
            a30 = __builtin_fmaf(hv.w, wv.x, a30);
            a31 = __builtin_fmaf(hv.w, wv.y, a31);
            a32 = __builtin_fmaf(hv.w, wv.z, a32);
            a33 = __builtin_fmaf(hv.w, wv.w, a33);
        }
        float4 bv = *(const float4*)&b2[d0];
        float4 o0 = make_float4(a00 + bv.x, a01 + bv.y, a02 + bv.z, a03 + bv.w);
        float4 o1 = make_float4(a10 + bv.x, a11 + bv.y, a12 + bv.z, a13 + bv.w);
        float4 o2 = make_float4(a20 + bv.x, a21 + bv.y, a22 + bv.z, a23 + bv.w);
        float4 o3 = make_float4(a30 + bv.x, a31 + bv.y, a32 + bv.z, a33 + bv.w);
        *(float4*)&out[(size_t)(tokBase + t0 + 0) * ND + d0] = o0;
        *(float4*)&out[(size_t)(tokBase + t0 + 1) * ND + d0] = o1;
        *(float4*)&out[(size_t)(tokBase + t0 + 2) * ND + d0] = o2;
        *(float4*)&out[(size_t)(tokBase + t0 + 3) * ND + d0] = o3;
    }
}

extern "C" void kernel_launch(void* const* d_in, const int* in_sizes, int n_in,
                              void* d_out, int out_size, void* d_ws, size_t ws_size,
                              hipStream_t stream) {
    const float* tok  = (const float*)d_in[0];
    const int*   mask = (const int*)d_in[1];   // layout auto-detected in-kernel
    const float* W1   = (const float*)d_in[2];
    const float* b1   = (const float*)d_in[3];
    const float* W2   = (const float*)d_in[4];
    const float* b2   = (const float*)d_in[5];
    float*       out  = (float*)d_out;

    float4* P       = (float4*)d_ws;                              // 512 KB
    float*  massBuf = (float*)((char*)d_ws + (size_t)NB * NT * sizeof(float4)); // 384 KB

    compute_P_kernel<<<dim3(NB * NT / 256), dim3(256), 0, stream>>>(tok, mask, P);

    dim3 gB(NT / 64, NB);
    topk_mass_kernel<<<gB, dim3(64), 0, stream>>>(P, mask, massBuf);

    mlp_kernel<<<dim3(NB * NT / 64), dim3(256), 0, stream>>>(massBuf, W1, b1, W2, b2, out);
}

// Round 3
// 183.203 us; speedup vs baseline: 2.3831x; 2.3831x over previous
//
#include <hip/hip_runtime.h>
#include <hip/hip_bf16.h>
#include <math.h>

#define NB 16
#define NT 2048
#define ND 512
#define NH 64

// ---------------------------------------------------------------------------
// mask dtype robustness: harness may ship jnp bool as int32 (0/1), as raw
// bytes, or f32. lengths >= T/2, so mask[0..3] are all true. Byte layout ->
// first int32 reads 0x01010101; int32 layout -> 1; f32 layout -> 0x3F800000.
// ---------------------------------------------------------------------------
__device__ __forceinline__ bool mask_is_bytes(const int* m) {
    return m[0] == 0x01010101;
}
__device__ __forceinline__ bool mask_at(const int* m, bool bytes, int i) {
    if (bytes) return ((const unsigned char*)m)[i] != 0;
    return m[i] != 0;
}

// Minkowski dot with metric folded into `a` = (E, -px, -py, -pz).
// Explicit fmaf so pass 1 and pass 2 produce bitwise-identical values.
__device__ __forceinline__ float dot4(float4 a, float4 p) {
    float d = a.x * p.x;
    d = __builtin_fmaf(a.y, p.y, d);
    d = __builtin_fmaf(a.z, p.z, d);
    d = __builtin_fmaf(a.w, p.w, d);
    return d;
}

// ---------------------------------------------------------------------------
// Kernel A: tokens_cont -> four-vectors P. Masked s-slots get (-1e30,0,0,0)
// so their dot with any valid row (~ -1e30*E_t ~ -1e32, finite) is far below
// every real dot (|real| <= ~3e5) and never enters a valid row's top-8.
// ---------------------------------------------------------------------------
__global__ void __launch_bounds__(256) compute_P_kernel(
        const float* __restrict__ tok,
        const int* __restrict__ mask,
        float4* __restrict__ P) {
    const bool mb = mask_is_bytes(mask);
    int i = blockIdx.x * 256 + threadIdx.x;
    if (i >= NB * NT) return;
    float4 t = ((const float4*)tok)[i];
    float E = t.x, Pt = t.y, eta = t.z, phi = t.w;
    float px = Pt * cosf(phi);
    float py = Pt * sinf(phi);
    float pz = Pt * sinhf(fminf(fmaxf(eta, -20.f), 20.f));
    bool m = mask_at(mask, mb, i);
    P[i] = m ? make_float4(E, px, py, pz)
             : make_float4(-1e30f, 0.f, 0.f, 0.f);
}

// ---------------------------------------------------------------------------
// Kernel B: 512 threads = 8 waves per block; block owns 64 tokens (lane =
// token), each wave scans a 256-wide s-chunk. P-row staged in LDS (broadcast
// reads). Chunk-local top-8 via med3 chain -> LDS -> every wave merges the
// 64 candidates to get global th2/th4/th8 -> chunk partial sums -> wave 0
// reduces and writes masses. 4096 waves total (was 512).
// ---------------------------------------------------------------------------
__global__ void __launch_bounds__(512) topk_mass_kernel(
        const float4* __restrict__ P,
        const int* __restrict__ mask,
        float* __restrict__ massOut) {
    __shared__ float Plds[NT * 4];        // 32 KB  staged row
    __shared__ float vtop[8][8][64];      // 16 KB  per-wave top-8 per token
    __shared__ float psum[8][12][64];     // 24 KB  per-wave partial sums

    const int b    = blockIdx.y;
    const int t0   = blockIdx.x * 64;
    const int tid  = threadIdx.x;
    const int lane = tid & 63;
    const int w    = tid >> 6;            // wave id 0..7
    const bool mb  = mask_is_bytes(mask);

    // mask is monotone per row; if first token of group is masked, all are.
    if (!mask_at(mask, mb, b * NT + t0)) {
        if (tid < 64) {
            float mz = sqrtf(1e-8f);
            int o = (b * NT + t0 + lane) * 3;
            massOut[o + 0] = mz;
            massOut[o + 1] = mz;
            massOut[o + 2] = mz;
        }
        return;
    }

    // Stage the whole row: 2048 float4 across 512 threads (4 iters, coalesced).
    const float4* Pb = P + b * NT;
    for (int i = tid; i < NT; i += 512) {
        float4 v = Pb[i];
        *(float4*)&Plds[i * 4] = v;
    }
    __syncthreads();

    const int t = t0 + lane;
    const bool maskt = mask_at(mask, mb, b * NT + t);
    float4 pt = *(const float4*)&Plds[(t0 + lane) * 4];
    float4 a  = make_float4(pt.x, -pt.y, -pt.z, -pt.w);

    const float NEGBIG = -3.402823466e38f;
    float v0 = NEGBIG, v1 = NEGBIG, v2 = NEGBIG, v3 = NEGBIG;
    float v4 = NEGBIG, v5 = NEGBIG, v6 = NEGBIG, v7 = NEGBIG;

    const int sBeg = w * (NT / 8), sEnd = sBeg + (NT / 8);

    // Pass 1: chunk-local top-8. All reads from OLD regs each step (ILP-8).
#pragma unroll 4
    for (int s = sBeg; s < sEnd; ++s) {
        float4 ps = *(const float4*)&Plds[s * 4];   // broadcast read
        float d = dot4(a, ps);
        float n0 = fmaxf(v0, d);
        float n1 = __builtin_amdgcn_fmed3f(d, v0, v1);
        float n2 = __builtin_amdgcn_fmed3f(d, v1, v2);
        float n3 = __builtin_amdgcn_fmed3f(d, v2, v3);
        float n4 = __builtin_amdgcn_fmed3f(d, v3, v4);
        float n5 = __builtin_amdgcn_fmed3f(d, v4, v5);
        float n6 = __builtin_amdgcn_fmed3f(d, v5, v6);
        float n7 = __builtin_amdgcn_fmed3f(d, v6, v7);
        v0 = n0; v1 = n1; v2 = n2; v3 = n3;
        v4 = n4; v5 = n5; v6 = n6; v7 = n7;
    }

    vtop[w][0][lane] = v0; vtop[w][1][lane] = v1;
    vtop[w][2][lane] = v2; vtop[w][3][lane] = v3;
    vtop[w][4][lane] = v4; vtop[w][5][lane] = v5;
    vtop[w][6][lane] = v6; vtop[w][7][lane] = v7;
    __syncthreads();

    // Merge 64 candidates -> global top-8. Every wave does this redundantly
    // so th* are available in-register for pass 2 with no extra barrier.
    float m0 = NEGBIG, m1 = NEGBIG, m2_ = NEGBIG, m3 = NEGBIG;
    float m4 = NEGBIG, m5 = NEGBIG, m6 = NEGBIG, m7 = NEGBIG;
#pragma unroll
    for (int w2 = 0; w2 < 8; ++w2) {
#pragma unroll
        for (int j = 0; j < 8; ++j) {
            float d = vtop[w2][j][lane];            // lane-contiguous, no conflict
            float n0 = fmaxf(m0, d);
            float n1 = __builtin_amdgcn_fmed3f(d, m0, m1);
            float n2 = __builtin_amdgcn_fmed3f(d, m1, m2_);
            float n3 = __builtin_amdgcn_fmed3f(d, m2_, m3);
            float n4 = __builtin_amdgcn_fmed3f(d, m3, m4);
            float n5 = __builtin_amdgcn_fmed3f(d, m4, m5);
            float n6 = __builtin_amdgcn_fmed3f(d, m5, m6);
            float n7 = __builtin_amdgcn_fmed3f(d, m6, m7);
            m0 = n0; m1 = n1; m2_ = n2; m3 = n3;
            m4 = n4; m5 = n5; m6 = n6; m7 = n7;
        }
    }
    const float th2 = m1, th4 = m3, th8 = m7;

    // Pass 2: chunk partial sums; dot recomputed bitwise-identically.
    float s2x = 0.f, s2y = 0.f, s2z = 0.f, s2w = 0.f;
    float s4x = 0.f, s4y = 0.f, s4z = 0.f, s4w = 0.f;
    float s8x = 0.f, s8y = 0.f, s8z = 0.f, s8w = 0.f;
#pragma unroll 4
    for (int s = sBeg; s < sEnd; ++s) {
        float4 ps = *(const float4*)&Plds[s * 4];
        float d = dot4(a, ps);
        if (d >= th8) {
            s8x += ps.x; s8y += ps.y; s8z += ps.z; s8w += ps.w;
            if (d >= th4) {
                s4x += ps.x; s4y += ps.y; s4z += ps.z; s4w += ps.w;
                if (d >= th2) {
                    s2x += ps.x; s2y += ps.y; s2z += ps.z; s2w += ps.w;
                }
            }
        }
    }
    psum[w][0][lane] = s2x;  psum[w][1][lane] = s2y;
    psum[w][2][lane] = s2z;  psum[w][3][lane] = s2w;
    psum[w][4][lane] = s4x;  psum[w][5][lane] = s4y;
    psum[w][6][lane] = s4z;  psum[w][7][lane] = s4w;
    psum[w][8][lane] = s8x;  psum[w][9][lane] = s8y;
    psum[w][10][lane] = s8z; psum[w][11][lane] = s8w;
    __syncthreads();

    if (tid < 64) {
        float tot[12];
#pragma unroll
        for (int c = 0; c < 12; ++c) {
            float acc = 0.f;
#pragma unroll
            for (int w2 = 0; w2 < 8; ++w2) acc += psum[w2][c][lane];
            tot[c] = acc;
        }
        auto massf = [&](float sx, float sy, float sz, float sw) -> float {
            float q = sx * sx;
            q = __builtin_fmaf(-sy, sy, q);
            q = __builtin_fmaf(-sz, sz, q);
            q = __builtin_fmaf(-sw, sw, q);
            q = fmaxf(q, 0.f);
            if (!maskt) q = 0.f;     // masked rows: inf/NaN garbage -> 0
            return sqrtf(q + 1e-8f);
        };
        int o = (b * NT + t) * 3;
        massOut[o + 0] = massf(tot[0], tot[1], tot[2], tot[3]);
        massOut[o + 1] = massf(tot[4], tot[5], tot[6], tot[7]);
        massOut[o + 2] = massf(tot[8], tot[9], tot[10], tot[11]);
    }
}

// ---------------------------------------------------------------------------
// Kernel C: mass(3) -> gelu(mass@W1+b1)(64) in LDS -> @W2+b2 (512).
// Block = 256 threads, 64 tokens per block. h stored k-major so the GEMM
// phase reads 4 tokens per ds_read_b128.
// ---------------------------------------------------------------------------
__global__ void __launch_bounds__(256) mlp_kernel(
        const float* __restrict__ mass,
        const float* __restrict__ W1,
        const float* __restrict__ b1,
        const float* __restrict__ W2,
        const float* __restrict__ b2,
        float* __restrict__ out) {
    __shared__ float hs[NH][64];        // [k][token]

    const int tid = threadIdx.x;
    const int tokBase = blockIdx.x * 64;

    {
        const int tt = tid & 63;
        const int hr = tid >> 6;        // 0..3, wave-uniform
        const int tokg = tokBase + tt;
        float m0 = mass[tokg * 3 + 0];
        float m1 = mass[tokg * 3 + 1];
        float m2 = mass[tokg * 3 + 2];
#pragma unroll
        for (int j = 0; j < 16; ++j) {
            int hh = hr + j * 4;
            float pre = b1[hh];
            pre = __builtin_fmaf(m0, W1[hh], pre);
            pre = __builtin_fmaf(m1, W1[NH + hh], pre);
            pre = __builtin_fmaf(m2, W1[2 * NH + hh], pre);
            float g = 0.5f * pre * (1.0f + erff(pre * 0.70710678118654752f));
            hs[hh][tt] = g;
        }
    }
    __syncthreads();

    const int dg = tid & 15;
    const int tg = tid >> 4;
    const int t0 = tg * 4;

    for (int dc = 0; dc < 8; ++dc) {
        const int d0 = dc * 64 + dg * 4;
        float a00 = 0, a01 = 0, a02 = 0, a03 = 0;
        float a10 = 0, a11 = 0, a12 = 0, a13 = 0;
        float a20 = 0, a21 = 0, a22 = 0, a23 = 0;
        float a30 = 0, a31 = 0, a32 = 0, a33 = 0;
#pragma unroll 4
        for (int k = 0; k < NH; ++k) {
            float4 hv = *(const float4*)&hs[k][t0];
            float4 wv = *(const float4*)&W2[k * ND + d0];
            a00 = __builtin_fmaf(hv.x, wv.x, a00);
            a01 = __builtin_fmaf(hv.x, wv.y, a01);
            a02 = __builtin_fmaf(hv.x, wv.z, a02);
            a03 = __builtin_fmaf(hv.x, wv.w, a03);
            a10 = __builtin_fmaf(hv.y, wv.x, a10);
            a11 = __builtin_fmaf(hv.y, wv.y, a11);
            a12 = __builtin_fmaf(hv.y, wv.z, a12);
            a13 = __builtin_fmaf(hv.y, wv.w, a13);
            a20 = __builtin_fmaf(hv.z, wv.x, a20);
            a21 = __builtin_fmaf(hv.z, wv.y, a21);
            a22 = __builtin_fmaf(hv.z, wv.z, a22);
            a23 = __builtin_fmaf(hv.z, wv.w, a23);
            a30 = __builtin_fmaf(hv.w, wv.x, a30);
            a31 = __builtin_fmaf(hv.w, wv.y, a31);
            a32 = __builtin_fmaf(hv.w, wv.z, a32);
            a33 = __builtin_fmaf(hv.w, wv.w, a33);
        }
        float4 bv = *(const float4*)&b2[d0];
        float4 o0 = make_float4(a00 + bv.x, a01 + bv.y, a02 + bv.z, a03 + bv.w);
        float4 o1 = make_float4(a10 + bv.x, a11 + bv.y, a12 + bv.z, a13 + bv.w);
        float4 o2 = make_float4(a20 + bv.x, a21 + bv.y, a22 + bv.z, a23 + bv.w);
        float4 o3 = make_float4(a30 + bv.x, a31 + bv.y, a32 + bv.z, a33 + bv.w);
        *(float4*)&out[(size_t)(tokBase + t0 + 0) * ND + d0] = o0;
        *(float4*)&out[(size_t)(tokBase + t0 + 1) * ND + d0] = o1;
        *(float4*)&out[(size_t)(tokBase + t0 + 2) * ND + d0] = o2;
        *(float4*)&out[(size_t)(tokBase + t0 + 3) * ND + d0] = o3;
    }
}

extern "C" void kernel_launch(void* const* d_in, const int* in_sizes, int n_in,
                              void* d_out, int out_size, void* d_ws, size_t ws_size,
                              hipStream_t stream) {
    const float* tok  = (const float*)d_in[0];
    const int*   mask = (const int*)d_in[1];   // layout auto-detected in-kernel
    const float* W1   = (const float*)d_in[2];
    const float* b1   = (const float*)d_in[3];
    const float* W2   = (const float*)d_in[4];
    const float* b2   = (const float*)d_in[5];
    float*       out  = (float*)d_out;

    float4* P       = (float4*)d_ws;                              // 512 KB
    float*  massBuf = (float*)((char*)d_ws + (size_t)NB * NT * sizeof(float4)); // 384 KB

    compute_P_kernel<<<dim3(NB * NT / 256), dim3(256), 0, stream>>>(tok, mask, P);

    dim3 gB(NT / 64, NB);
    topk_mass_kernel<<<gB, dim3(512), 0, stream>>>(P, mask, massBuf);

    mlp_kernel<<<dim3(NB * NT / 64), dim3(256), 0, stream>>>(massBuf, W1, b1, W2, b2, out);
}

// Round 4
// 153.175 us; speedup vs baseline: 2.8502x; 1.1960x over previous
//
#include <hip/hip_runtime.h>
#include <hip/hip_bf16.h>
#include <math.h>

#define NB 16
#define NT 2048
#define ND 512
#define NH 64

typedef __attribute__((ext_vector_type(8))) short short8;
typedef __attribute__((ext_vector_type(4))) float float4v;

// ---------------------------------------------------------------------------
// mask dtype robustness: byte layout -> first int32 reads 0x01010101 (lengths
// >= T/2 so mask[0..3] all true); int32 layout -> 1; f32 layout -> 0x3F800000.
// ---------------------------------------------------------------------------
__device__ __forceinline__ bool mask_is_bytes(const int* m) {
    return m[0] == 0x01010101;
}
__device__ __forceinline__ bool mask_at(const int* m, bool bytes, int i) {
    if (bytes) return ((const unsigned char*)m)[i] != 0;
    return m[i] != 0;
}

__device__ __forceinline__ float dot4(float4 a, float4 p) {
    float d = a.x * p.x;
    d = __builtin_fmaf(a.y, p.y, d);
    d = __builtin_fmaf(a.z, p.z, d);
    d = __builtin_fmaf(a.w, p.w, d);
    return d;
}

// round-to-nearest-even f32 -> bf16 (values are finite here)
__device__ __forceinline__ unsigned short f2bf(float x) {
    unsigned int u = __float_as_uint(x);
    u += 0x7fffu + ((u >> 16) & 1u);
    return (unsigned short)(u >> 16);
}

// ---------------------------------------------------------------------------
// Kernel A: tokens -> four-vectors P (masked slots = (-1e30,0,0,0)), PLUS
// one-time W2 fp32[k][n] -> bf16 W2t[n][k] conversion (1 elem/thread; grid
// 128x256 == 32768 == 512*64 exactly).
// ---------------------------------------------------------------------------
__global__ void __launch_bounds__(256) compute_P_kernel(
        const float* __restrict__ tok,
        const int* __restrict__ mask,
        float4* __restrict__ P,
        unsigned short* __restrict__ W2t,
        const float* __restrict__ W2) {
    const bool mb = mask_is_bytes(mask);
    int i = blockIdx.x * 256 + threadIdx.x;

    float4 t = ((const float4*)tok)[i];
    float E = t.x, Pt = t.y, eta = t.z, phi = t.w;
    float px = Pt * cosf(phi);
    float py = Pt * sinf(phi);
    float pz = Pt * sinhf(fminf(fmaxf(eta, -20.f), 20.f));
    bool m = mask_at(mask, mb, i);
    P[i] = m ? make_float4(E, px, py, pz)
             : make_float4(-1e30f, 0.f, 0.f, 0.f);

    // W2t: n = i&511 (coalesced read), k = i>>9
    int n = i & 511, k = i >> 9;
    W2t[n * NH + k] = f2bf(W2[k * ND + n]);
}

// ---------------------------------------------------------------------------
// Kernel B (unchanged from R3): 8 waves/block, block owns 64 tokens, P-row in
// LDS, chunk-local top-8 med3 chains -> merge -> exact-membership pass 2.
// ---------------------------------------------------------------------------
__global__ void __launch_bounds__(512) topk_mass_kernel(
        const float4* __restrict__ P,
        const int* __restrict__ mask,
        float* __restrict__ massOut) {
    __shared__ float Plds[NT * 4];
    __shared__ float vtop[8][8][64];
    __shared__ float psum[8][12][64];

    const int b    = blockIdx.y;
    const int t0   = blockIdx.x * 64;
    const int tid  = threadIdx.x;
    const int lane = tid & 63;
    const int w    = tid >> 6;
    const bool mb  = mask_is_bytes(mask);

    if (!mask_at(mask, mb, b * NT + t0)) {
        if (tid < 64) {
            float mz = sqrtf(1e-8f);
            int o = (b * NT + t0 + lane) * 3;
            massOut[o + 0] = mz;
            massOut[o + 1] = mz;
            massOut[o + 2] = mz;
        }
        return;
    }

    const float4* Pb = P + b * NT;
    for (int i = tid; i < NT; i += 512) {
        float4 v = Pb[i];
        *(float4*)&Plds[i * 4] = v;
    }
    __syncthreads();

    const int t = t0 + lane;
    const bool maskt = mask_at(mask, mb, b * NT + t);
    float4 pt = *(const float4*)&Plds[(t0 + lane) * 4];
    float4 a  = make_float4(pt.x, -pt.y, -pt.z, -pt.w);

    const float NEGBIG = -3.402823466e38f;
    float v0 = NEGBIG, v1 = NEGBIG, v2 = NEGBIG, v3 = NEGBIG;
    float v4 = NEGBIG, v5 = NEGBIG, v6 = NEGBIG, v7 = NEGBIG;

    const int sBeg = w * (NT / 8), sEnd = sBeg + (NT / 8);

#pragma unroll 4
    for (int s = sBeg; s < sEnd; ++s) {
        float4 ps = *(const float4*)&Plds[s * 4];
        float d = dot4(a, ps);
        float n0 = fmaxf(v0, d);
        float n1 = __builtin_amdgcn_fmed3f(d, v0, v1);
        float n2 = __builtin_amdgcn_fmed3f(d, v1, v2);
        float n3 = __builtin_amdgcn_fmed3f(d, v2, v3);
        float n4 = __builtin_amdgcn_fmed3f(d, v3, v4);
        float n5 = __builtin_amdgcn_fmed3f(d, v4, v5);
        float n6 = __builtin_amdgcn_fmed3f(d, v5, v6);
        float n7 = __builtin_amdgcn_fmed3f(d, v6, v7);
        v0 = n0; v1 = n1; v2 = n2; v3 = n3;
        v4 = n4; v5 = n5; v6 = n6; v7 = n7;
    }

    vtop[w][0][lane] = v0; vtop[w][1][lane] = v1;
    vtop[w][2][lane] = v2; vtop[w][3][lane] = v3;
    vtop[w][4][lane] = v4; vtop[w][5][lane] = v5;
    vtop[w][6][lane] = v6; vtop[w][7][lane] = v7;
    __syncthreads();

    float m0 = NEGBIG, m1 = NEGBIG, m2_ = NEGBIG, m3 = NEGBIG;
    float m4 = NEGBIG, m5 = NEGBIG, m6 = NEGBIG, m7 = NEGBIG;
#pragma unroll
    for (int w2 = 0; w2 < 8; ++w2) {
#pragma unroll
        for (int j = 0; j < 8; ++j) {
            float d = vtop[w2][j][lane];
            float n0 = fmaxf(m0, d);
            float n1 = __builtin_amdgcn_fmed3f(d, m0, m1);
            float n2 = __builtin_amdgcn_fmed3f(d, m1, m2_);
            float n3 = __builtin_amdgcn_fmed3f(d, m2_, m3);
            float n4 = __builtin_amdgcn_fmed3f(d, m3, m4);
            float n5 = __builtin_amdgcn_fmed3f(d, m4, m5);
            float n6 = __builtin_amdgcn_fmed3f(d, m5, m6);
            float n7 = __builtin_amdgcn_fmed3f(d, m6, m7);
            m0 = n0; m1 = n1; m2_ = n2; m3 = n3;
            m4 = n4; m5 = n5; m6 = n6; m7 = n7;
        }
    }
    const float th2 = m1, th4 = m3, th8 = m7;

    float s2x = 0.f, s2y = 0.f, s2z = 0.f, s2w = 0.f;
    float s4x = 0.f, s4y = 0.f, s4z = 0.f, s4w = 0.f;
    float s8x = 0.f, s8y = 0.f, s8z = 0.f, s8w = 0.f;
#pragma unroll 4
    for (int s = sBeg; s < sEnd; ++s) {
        float4 ps = *(const float4*)&Plds[s * 4];
        float d = dot4(a, ps);
        if (d >= th8) {
            s8x += ps.x; s8y += ps.y; s8z += ps.z; s8w += ps.w;
            if (d >= th4) {
                s4x += ps.x; s4y += ps.y; s4z += ps.z; s4w += ps.w;
                if (d >= th2) {
                    s2x += ps.x; s2y += ps.y; s2z += ps.z; s2w += ps.w;
                }
            }
        }
    }
    psum[w][0][lane] = s2x;  psum[w][1][lane] = s2y;
    psum[w][2][lane] = s2z;  psum[w][3][lane] = s2w;
    psum[w][4][lane] = s4x;  psum[w][5][lane] = s4y;
    psum[w][6][lane] = s4z;  psum[w][7][lane] = s4w;
    psum[w][8][lane] = s8x;  psum[w][9][lane] = s8y;
    psum[w][10][lane] = s8z; psum[w][11][lane] = s8w;
    __syncthreads();

    if (tid < 64) {
        float tot[12];
#pragma unroll
        for (int c = 0; c < 12; ++c) {
            float acc = 0.f;
#pragma unroll
            for (int w2 = 0; w2 < 8; ++w2) acc += psum[w2][c][lane];
            tot[c] = acc;
        }
        auto massf = [&](float sx, float sy, float sz, float sw) -> float {
            float q = sx * sx;
            q = __builtin_fmaf(-sy, sy, q);
            q = __builtin_fmaf(-sz, sz, q);
            q = __builtin_fmaf(-sw, sw, q);
            q = fmaxf(q, 0.f);
            if (!maskt) q = 0.f;
            return sqrtf(q + 1e-8f);
        };
        int o = (b * NT + t) * 3;
        massOut[o + 0] = massf(tot[0], tot[1], tot[2], tot[3]);
        massOut[o + 1] = massf(tot[4], tot[5], tot[6], tot[7]);
        massOut[o + 2] = massf(tot[8], tot[9], tot[10], tot[11]);
    }
}

// ---------------------------------------------------------------------------
// Kernel C: MFMA MLP. Block = 256 thr (4 waves), 32 tokens. Stage 1: h=gelu
// (mass@W1+b1) -> bf16 LDS [32][80] (160B rows: A-frag b128 reads ~conflict-
// free). Stage 2: each wave does M=32 x N=128 via 32 mfma_f32_16x16x32_bf16;
// B-frags straight from global W2t[n][k] (64 KB, L2-hot).
// Layouts: A[m=lane&15][k=quad*8+j]; B[n=lane&15][k=quad*8+j];
// D col=lane&15 (n), row=quad*4+reg (m).
// ---------------------------------------------------------------------------
__global__ void __launch_bounds__(256) mlp_kernel(
        const float* __restrict__ mass,
        const float* __restrict__ W1,
        const float* __restrict__ b1,
        const unsigned short* __restrict__ W2t,
        const float* __restrict__ b2,
        float* __restrict__ out) {
    __shared__ unsigned short hs[32][80];   // 5 KB, 160 B rows (16B-aligned)

    const int tid  = threadIdx.x;
    const int lane = tid & 63;
    const int wv   = tid >> 6;              // 0..3
    const int tokBase = blockIdx.x * 32;

    // Stage 1: thread (tt = tid&31, hr = tid>>5) computes h[tt][hr*8 .. +7].
    {
        const int tt = tid & 31;
        const int hr = tid >> 5;            // 0..7
        const int tokg = tokBase + tt;
        float m0 = mass[tokg * 3 + 0];
        float m1 = mass[tokg * 3 + 1];
        float m2 = mass[tokg * 3 + 2];
        unsigned short hv[8];
#pragma unroll
        for (int j = 0; j < 8; ++j) {
            int hh = hr * 8 + j;
            float pre = b1[hh];
            pre = __builtin_fmaf(m0, W1[hh], pre);
            pre = __builtin_fmaf(m1, W1[NH + hh], pre);
            pre = __builtin_fmaf(m2, W1[2 * NH + hh], pre);
            float g = 0.5f * pre * (1.0f + erff(pre * 0.70710678118654752f));
            hv[j] = f2bf(g);
        }
        *(short8*)&hs[tt][hr * 8] = *(const short8*)hv;
    }
    __syncthreads();

    // Stage 2
    const int col  = lane & 15;
    const int quad = lane >> 4;
    const int nBase = wv * 128;

    // A-frags [mtile][kstep]
    short8 afrag[2][2];
#pragma unroll
    for (int mt = 0; mt < 2; ++mt)
#pragma unroll
        for (int ks = 0; ks < 2; ++ks)
            afrag[mt][ks] = *(const short8*)&hs[mt * 16 + col][ks * 32 + quad * 8];

    float4v acc[2][8];
#pragma unroll
    for (int mt = 0; mt < 2; ++mt)
#pragma unroll
        for (int nt = 0; nt < 8; ++nt)
            acc[mt][nt] = (float4v)(0.f);

#pragma unroll
    for (int nt = 0; nt < 8; ++nt) {
        const unsigned short* wp = W2t + (nBase + nt * 16 + col) * NH + quad * 8;
        short8 bf0 = *(const short8*)(wp);
        short8 bf1 = *(const short8*)(wp + 32);
        acc[0][nt] = __builtin_amdgcn_mfma_f32_16x16x32_bf16(afrag[0][0], bf0, acc[0][nt], 0, 0, 0);
        acc[1][nt] = __builtin_amdgcn_mfma_f32_16x16x32_bf16(afrag[1][0], bf0, acc[1][nt], 0, 0, 0);
        acc[0][nt] = __builtin_amdgcn_mfma_f32_16x16x32_bf16(afrag[0][1], bf1, acc[0][nt], 0, 0, 0);
        acc[1][nt] = __builtin_amdgcn_mfma_f32_16x16x32_bf16(afrag[1][1], bf1, acc[1][nt], 0, 0, 0);
    }

    // Epilogue: + b2, store. Lane covers n = nBase + nt*16 + col,
    // m = mt*16 + quad*4 + r.
#pragma unroll
    for (int nt = 0; nt < 8; ++nt) {
        float bias = b2[nBase + nt * 16 + col];
#pragma unroll
        for (int mt = 0; mt < 2; ++mt) {
            int mRow = tokBase + mt * 16 + quad * 4;
            size_t base = (size_t)mRow * ND + nBase + nt * 16 + col;
#pragma unroll
            for (int r = 0; r < 4; ++r) {
                out[base + (size_t)r * ND] = acc[mt][nt][r] + bias;
            }
        }
    }
}

extern "C" void kernel_launch(void* const* d_in, const int* in_sizes, int n_in,
                              void* d_out, int out_size, void* d_ws, size_t ws_size,
                              hipStream_t stream) {
    const float* tok  = (const float*)d_in[0];
    const int*   mask = (const int*)d_in[1];
    const float* W1   = (const float*)d_in[2];
    const float* b1   = (const float*)d_in[3];
    const float* W2   = (const float*)d_in[4];
    const float* b2   = (const float*)d_in[5];
    float*       out  = (float*)d_out;

    float4*         P       = (float4*)d_ws;                                   // 512 KB
    float*          massBuf = (float*)((char*)d_ws + (size_t)NB * NT * 16);    // 384 KB
    unsigned short* W2t     = (unsigned short*)((char*)d_ws + (size_t)NB * NT * 16
                                                + (size_t)NB * NT * 3 * 4);    // 64 KB

    compute_P_kernel<<<dim3(NB * NT / 256), dim3(256), 0, stream>>>(tok, mask, P, W2t, W2);

    dim3 gB(NT / 64, NB);
    topk_mass_kernel<<<gB, dim3(512), 0, stream>>>(P, mask, massBuf);

    mlp_kernel<<<dim3(NB * NT / 32), dim3(256), 0, stream>>>(massBuf, W1, b1, W2t, b2, out);
}

// Round 6
// 141.471 us; speedup vs baseline: 3.0860x; 1.0827x over previous
//
#include <hip/hip_runtime.h>
#include <hip/hip_bf16.h>
#include <math.h>

#define NB 16
#define NT 2048
#define ND 512
#define NH 64

typedef __attribute__((ext_vector_type(8))) short short8;
typedef __attribute__((ext_vector_type(4))) float float4v;

// ---------------------------------------------------------------------------
// mask dtype robustness: byte layout -> first int32 reads 0x01010101 (lengths
// >= T/2 so mask[0..3] all true); int32 layout -> 1; f32 layout -> 0x3F800000.
// ---------------------------------------------------------------------------
__device__ __forceinline__ bool mask_is_bytes(const int* m) {
    return m[0] == 0x01010101;
}
__device__ __forceinline__ bool mask_at(const int* m, bool bytes, int i) {
    if (bytes) return ((const unsigned char*)m)[i] != 0;
    return m[i] != 0;
}

__device__ __forceinline__ float dot4(float4 a, float4 p) {
    float d = a.x * p.x;
    d = __builtin_fmaf(a.y, p.y, d);
    d = __builtin_fmaf(a.z, p.z, d);
    d = __builtin_fmaf(a.w, p.w, d);
    return d;
}

// round-to-nearest-even f32 -> bf16 (values are finite here)
__device__ __forceinline__ unsigned short f2bf(float x) {
    unsigned int u = __float_as_uint(x);
    u += 0x7fffu + ((u >> 16) & 1u);
    return (unsigned short)(u >> 16);
}

// ---------------------------------------------------------------------------
// Kernel A: tokens -> four-vectors P (masked slots = (-1e30,0,0,0)), PLUS
// one-time W2 fp32[k][n] -> bf16 W2t[n][k] conversion (1 elem/thread; grid
// 128x256 == 32768 == 512*64 exactly).
// ---------------------------------------------------------------------------
__global__ void __launch_bounds__(256) compute_P_kernel(
        const float* __restrict__ tok,
        const int* __restrict__ mask,
        float4* __restrict__ P,
        unsigned short* __restrict__ W2t,
        const float* __restrict__ W2) {
    const bool mb = mask_is_bytes(mask);
    int i = blockIdx.x * 256 + threadIdx.x;

    float4 t = ((const float4*)tok)[i];
    float E = t.x, Pt = t.y, eta = t.z, phi = t.w;
    float px = Pt * cosf(phi);
    float py = Pt * sinf(phi);
    float pz = Pt * sinhf(fminf(fmaxf(eta, -20.f), 20.f));
    bool m = mask_at(mask, mb, i);
    P[i] = m ? make_float4(E, px, py, pz)
             : make_float4(-1e30f, 0.f, 0.f, 0.f);

    // W2t: n = i&511 (coalesced read), k = i>>9
    int n = i & 511, k = i >> 9;
    W2t[n * NH + k] = f2bf(W2[k * ND + n]);
}

// ---------------------------------------------------------------------------
// Kernel B (R4 structure + L-trim): 8 waves/block, block owns 64 tokens,
// P-row in LDS, chunk-local top-8 med3 chains -> merge -> exact-membership
// pass 2. NEW: valid length L counted during staging (Px == -1e30 marks
// masked; mask monotone), both scans trimmed to [0, L) split 8 ways.
// ---------------------------------------------------------------------------
__global__ void __launch_bounds__(512) topk_mass_kernel(
        const float4* __restrict__ P,
        const int* __restrict__ mask,
        float* __restrict__ massOut) {
    __shared__ float Plds[NT * 4];
    __shared__ float vtop[8][8][64];
    __shared__ float psum[8][12][64];
    __shared__ int wcnt[8];

    const int b    = blockIdx.y;
    const int t0   = blockIdx.x * 64;
    const int tid  = threadIdx.x;
    const int lane = tid & 63;
    const int w    = tid >> 6;
    const bool mb  = mask_is_bytes(mask);

    if (!mask_at(mask, mb, b * NT + t0)) {
        if (tid < 64) {
            float mz = sqrtf(1e-8f);
            int o = (b * NT + t0 + lane) * 3;
            massOut[o + 0] = mz;
            massOut[o + 1] = mz;
            massOut[o + 2] = mz;
        }
        return;
    }

    const float4* Pb = P + b * NT;
    int cnt = 0;
    for (int i = tid; i < NT; i += 512) {
        float4 v = Pb[i];
        *(float4*)&Plds[i * 4] = v;
        cnt += (int)__popcll(__ballot(v.x != -1e30f));
    }
    if (lane == 0) wcnt[w] = cnt;
    __syncthreads();

    int L = 0;
#pragma unroll
    for (int j = 0; j < 8; ++j) L += wcnt[j];
    const int C    = (L + 7) >> 3;
    const int sBeg = w * C;
    const int sEnd = min(sBeg + C, L);

    const int t = t0 + lane;
    const bool maskt = mask_at(mask, mb, b * NT + t);
    float4 pt = *(const float4*)&Plds[(t0 + lane) * 4];
    float4 a  = make_float4(pt.x, -pt.y, -pt.z, -pt.w);

    const float NEGBIG = -3.402823466e38f;
    float v0 = NEGBIG, v1 = NEGBIG, v2 = NEGBIG, v3 = NEGBIG;
    float v4 = NEGBIG, v5 = NEGBIG, v6 = NEGBIG, v7 = NEGBIG;

#pragma unroll 4
    for (int s = sBeg; s < sEnd; ++s) {
        float4 ps = *(const float4*)&Plds[s * 4];
        float d = dot4(a, ps);
        float n0 = fmaxf(v0, d);
        float n1 = __builtin_amdgcn_fmed3f(d, v0, v1);
        float n2 = __builtin_amdgcn_fmed3f(d, v1, v2);
        float n3 = __builtin_amdgcn_fmed3f(d, v2, v3);
        float n4 = __builtin_amdgcn_fmed3f(d, v3, v4);
        float n5 = __builtin_amdgcn_fmed3f(d, v4, v5);
        float n6 = __builtin_amdgcn_fmed3f(d, v5, v6);
        float n7 = __builtin_amdgcn_fmed3f(d, v6, v7);
        v0 = n0; v1 = n1; v2 = n2; v3 = n3;
        v4 = n4; v5 = n5; v6 = n6; v7 = n7;
    }

    vtop[w][0][lane] = v0; vtop[w][1][lane] = v1;
    vtop[w][2][lane] = v2; vtop[w][3][lane] = v3;
    vtop[w][4][lane] = v4; vtop[w][5][lane] = v5;
    vtop[w][6][lane] = v6; vtop[w][7][lane] = v7;
    __syncthreads();

    float m0 = NEGBIG, m1 = NEGBIG, m2_ = NEGBIG, m3 = NEGBIG;
    float m4 = NEGBIG, m5 = NEGBIG, m6 = NEGBIG, m7 = NEGBIG;
#pragma unroll
    for (int w2 = 0; w2 < 8; ++w2) {
#pragma unroll
        for (int j = 0; j < 8; ++j) {
            float d = vtop[w2][j][lane];
            float n0 = fmaxf(m0, d);
            float n1 = __builtin_amdgcn_fmed3f(d, m0, m1);
            float n2 = __builtin_amdgcn_fmed3f(d, m1, m2_);
            float n3 = __builtin_amdgcn_fmed3f(d, m2_, m3);
            float n4 = __builtin_amdgcn_fmed3f(d, m3, m4);
            float n5 = __builtin_amdgcn_fmed3f(d, m4, m5);
            float n6 = __builtin_amdgcn_fmed3f(d, m5, m6);
            float n7 = __builtin_amdgcn_fmed3f(d, m6, m7);
            m0 = n0; m1 = n1; m2_ = n2; m3 = n3;
            m4 = n4; m5 = n5; m6 = n6; m7 = n7;
        }
    }
    const float th2 = m1, th4 = m3, th8 = m7;

    float s2x = 0.f, s2y = 0.f, s2z = 0.f, s2w = 0.f;
    float s4x = 0.f, s4y = 0.f, s4z = 0.f, s4w = 0.f;
    float s8x = 0.f, s8y = 0.f, s8z = 0.f, s8w = 0.f;
#pragma unroll 4
    for (int s = sBeg; s < sEnd; ++s) {
        float4 ps = *(const float4*)&Plds[s * 4];
        float d = dot4(a, ps);
        if (d >= th8) {
            s8x += ps.x; s8y += ps.y; s8z += ps.z; s8w += ps.w;
            if (d >= th4) {
                s4x += ps.x; s4y += ps.y; s4z += ps.z; s4w += ps.w;
                if (d >= th2) {
                    s2x += ps.x; s2y += ps.y; s2z += ps.z; s2w += ps.w;
                }
            }
        }
    }
    psum[w][0][lane] = s2x;  psum[w][1][lane] = s2y;
    psum[w][2][lane] = s2z;  psum[w][3][lane] = s2w;
    psum[w][4][lane] = s4x;  psum[w][5][lane] = s4y;
    psum[w][6][lane] = s4z;  psum[w][7][lane] = s4w;
    psum[w][8][lane] = s8x;  psum[w][9][lane] = s8y;
    psum[w][10][lane] = s8z; psum[w][11][lane] = s8w;
    __syncthreads();

    if (tid < 64) {
        float tot[12];
#pragma unroll
        for (int c = 0; c < 12; ++c) {
            float acc = 0.f;
#pragma unroll
            for (int w2 = 0; w2 < 8; ++w2) acc += psum[w2][c][lane];
            tot[c] = acc;
        }
        auto massf = [&](float sx, float sy, float sz, float sw) -> float {
            float q = sx * sx;
            q = __builtin_fmaf(-sy, sy, q);
            q = __builtin_fmaf(-sz, sz, q);
            q = __builtin_fmaf(-sw, sw, q);
            q = fmaxf(q, 0.f);
            if (!maskt) q = 0.f;
            return sqrtf(q + 1e-8f);
        };
        int o = (b * NT + t) * 3;
        massOut[o + 0] = massf(tot[0], tot[1], tot[2], tot[3]);
        massOut[o + 1] = massf(tot[4], tot[5], tot[6], tot[7]);
        massOut[o + 2] = massf(tot[8], tot[9], tot[10], tot[11]);
    }
}

// ---------------------------------------------------------------------------
// Kernel C (unchanged R4): MFMA MLP. Block = 256 thr (4 waves), 32 tokens.
// Layouts: A[m=lane&15][k=quad*8+j]; B[n=lane&15][k=quad*8+j];
// D col=lane&15 (n), row=quad*4+reg (m).
// ---------------------------------------------------------------------------
__global__ void __launch_bounds__(256) mlp_kernel(
        const float* __restrict__ mass,
        const float* __restrict__ W1,
        const float* __restrict__ b1,
        const unsigned short* __restrict__ W2t,
        const float* __restrict__ b2,
        float* __restrict__ out) {
    __shared__ unsigned short hs[32][80];   // 5 KB, 160 B rows (16B-aligned)

    const int tid  = threadIdx.x;
    const int lane = tid & 63;
    const int wv   = tid >> 6;              // 0..3
    const int tokBase = blockIdx.x * 32;

    {
        const int tt = tid & 31;
        const int hr = tid >> 5;            // 0..7
        const int tokg = tokBase + tt;
        float m0 = mass[tokg * 3 + 0];
        float m1 = mass[tokg * 3 + 1];
        float m2 = mass[tokg * 3 + 2];
        unsigned short hv[8];
#pragma unroll
        for (int j = 0; j < 8; ++j) {
            int hh = hr * 8 + j;
            float pre = b1[hh];
            pre = __builtin_fmaf(m0, W1[hh], pre);
            pre = __builtin_fmaf(m1, W1[NH + hh], pre);
            pre = __builtin_fmaf(m2, W1[2 * NH + hh], pre);
            float g = 0.5f * pre * (1.0f + erff(pre * 0.70710678118654752f));
            hv[j] = f2bf(g);
        }
        *(short8*)&hs[tt][hr * 8] = *(const short8*)hv;
    }
    __syncthreads();

    const int col  = lane & 15;
    const int quad = lane >> 4;
    const int nBase = wv * 128;

    short8 afrag[2][2];
#pragma unroll
    for (int mt = 0; mt < 2; ++mt)
#pragma unroll
        for (int ks = 0; ks < 2; ++ks)
            afrag[mt][ks] = *(const short8*)&hs[mt * 16 + col][ks * 32 + quad * 8];

    float4v acc[2][8];
#pragma unroll
    for (int mt = 0; mt < 2; ++mt)
#pragma unroll
        for (int nt = 0; nt < 8; ++nt)
            acc[mt][nt] = (float4v)(0.f);

#pragma unroll
    for (int nt = 0; nt < 8; ++nt) {
        const unsigned short* wp = W2t + (nBase + nt * 16 + col) * NH + quad * 8;
        short8 bf0 = *(const short8*)(wp);
        short8 bf1 = *(const short8*)(wp + 32);
        acc[0][nt] = __builtin_amdgcn_mfma_f32_16x16x32_bf16(afrag[0][0], bf0, acc[0][nt], 0, 0, 0);
        acc[1][nt] = __builtin_amdgcn_mfma_f32_16x16x32_bf16(afrag[1][0], bf0, acc[1][nt], 0, 0, 0);
        acc[0][nt] = __builtin_amdgcn_mfma_f32_16x16x32_bf16(afrag[0][1], bf1, acc[0][nt], 0, 0, 0);
        acc[1][nt] = __builtin_amdgcn_mfma_f32_16x16x32_bf16(afrag[1][1], bf1, acc[1][nt], 0, 0, 0);
    }

#pragma unroll
    for (int nt = 0; nt < 8; ++nt) {
        float bias = b2[nBase + nt * 16 + col];
#pragma unroll
        for (int mt = 0; mt < 2; ++mt) {
            int mRow = tokBase + mt * 16 + quad * 4;
            size_t base = (size_t)mRow * ND + nBase + nt * 16 + col;
#pragma unroll
            for (int r = 0; r < 4; ++r) {
                out[base + (size_t)r * ND] = acc[mt][nt][r] + bias;
            }
        }
    }
}

extern "C" void kernel_launch(void* const* d_in, const int* in_sizes, int n_in,
                              void* d_out, int out_size, void* d_ws, size_t ws_size,
                              hipStream_t stream) {
    const float* tok  = (const float*)d_in[0];
    const int*   mask = (const int*)d_in[1];
    const float* W1   = (const float*)d_in[2];
    const float* b1   = (const float*)d_in[3];
    const float* W2   = (const float*)d_in[4];
    const float* b2   = (const float*)d_in[5];
    float*       out  = (float*)d_out;

    float4*         P       = (float4*)d_ws;                                   // 512 KB
    float*          massBuf = (float*)((char*)d_ws + (size_t)NB * NT * 16);    // 384 KB
    unsigned short* W2t     = (unsigned short*)((char*)d_ws + (size_t)NB * NT * 16
                                                + (size_t)NB * NT * 3 * 4);    // 64 KB

    compute_P_kernel<<<dim3(NB * NT / 256), dim3(256), 0, stream>>>(tok, mask, P, W2t, W2);

    dim3 gB(NT / 64, NB);
    topk_mass_kernel<<<gB, dim3(512), 0, stream>>>(P, mask, massBuf);

    mlp_kernel<<<dim3(NB * NT / 32), dim3(256), 0, stream>>>(massBuf, W1, b1, W2t, b2, out);
}